// Round 1
// 802.714 us; speedup vs baseline: 1.0666x; 1.0666x over previous
//
#include <hip/hip_runtime.h>
#include <cstdint>
#include <cstddef>

#define S_LEN 2048
#define EMB   1024
#define NH    16
#define DH    64

typedef unsigned short u16;
typedef __attribute__((ext_vector_type(8))) short bf16x8;   // 8 bf16 (4 VGPRs)
typedef __attribute__((ext_vector_type(4))) float f32x4;

__device__ __forceinline__ u16 f2bf(float f) {
  unsigned int u = __float_as_uint(f);
  u = (u + 0x7fffu + ((u >> 16) & 1u)) >> 16;   // RNE
  return (u16)u;
}

__device__ __forceinline__ void gload16(const void* g, void* l) {
  __builtin_amdgcn_global_load_lds(
      (const __attribute__((address_space(1))) unsigned int*)g,
      (__attribute__((address_space(3))) unsigned int*)l, 16, 0, 0);
}

// One launch converts all 7 fp32 inputs to bf16.
// Layout of the flat f4 index space (all boundaries are powers of two,
// and every region is a whole number of 256-thread blocks):
//   [0, 3<<20)          : activations q,k,v   (1<<20 f4 each)
//   [3<<20, 3<<20+4<<18): weights qw,kw,vw,ow (1<<18 f4 each)
__global__ void cvt_all(
    const float* __restrict__ q_f, const float* __restrict__ k_f, const float* __restrict__ v_f,
    const float* __restrict__ qw_f, const float* __restrict__ kw_f,
    const float* __restrict__ vw_f, const float* __restrict__ ow_f,
    u16* __restrict__ xq, u16* __restrict__ xk, u16* __restrict__ xv,
    u16* __restrict__ wq, u16* __restrict__ wk, u16* __restrict__ wv, u16* __restrict__ wo) {
  int i = blockIdx.x * blockDim.x + threadIdx.x;
  const float* src;
  u16* dst;
  int off;
  if (i < (3 << 20)) {
    int r = i >> 20;
    off = i & ((1 << 20) - 1);
    src = (r == 0) ? q_f : (r == 1) ? k_f : v_f;
    dst = (r == 0) ? xq  : (r == 1) ? xk  : xv;
  } else {
    int j = i - (3 << 20);
    int r = j >> 18;
    off = j & ((1 << 18) - 1);
    src = (r == 0) ? qw_f : (r == 1) ? kw_f : (r == 2) ? vw_f : ow_f;
    dst = (r == 0) ? wq   : (r == 1) ? wk   : (r == 2) ? wv   : wo;
  }
  float4 v = ((const float4*)src)[off];
  ushort4 o;
  o.x = f2bf(v.x); o.y = f2bf(v.y); o.z = f2bf(v.z); o.w = f2bf(v.w);
  ((ushort4*)dst)[off] = o;
}

// C[m,n] = (sum_k A[m,k]*B[n,k] + bias[n]) * scale
// A: [M x K] bf16 row-major, B: [N x K] bf16 row-major (the W matrix, y = x W^T)
// mode 0: out[((b*NH+h)*S + s)*DH + d]   (Q,K -> [B,H,S,Dh] bf16)
// mode 1: out[((b*NH+h)*DH + d)*S + s]   (V   -> [B,H,Dh,S] bf16, transposed)
// mode 2: outf[m*EMB + n]                (final output, fp32 row-major)
__device__ __forceinline__ void gemm_tile(
    u16* a_sm, u16* b_sm,
    const u16* __restrict__ A, const u16* __restrict__ B,
    const float* __restrict__ bias, u16* __restrict__ out,
    float* __restrict__ outf, int K, float scale, int mode) {
  const int tid = threadIdx.x;
  const int lane = tid & 63, wv = tid >> 6;
  const int l16 = lane & 15, quad = lane >> 4;
  const int m0 = blockIdx.y * 128, n0 = blockIdx.x * 128;
  const int wrow = (wv >> 1) * 64, wcol = (wv & 1) * 64;
  const f32x4 fzero = {0.f, 0.f, 0.f, 0.f};

  f32x4 acc[4][4];
#pragma unroll
  for (int i = 0; i < 4; i++)
#pragma unroll
    for (int j = 0; j < 4; j++) acc[i][j] = fzero;

  const int srow = lane >> 3;        // 0..7 (row within 8-row chunk)
  const int scol = (lane & 7) * 8;   // element offset (8 bf16 = 16B)

  for (int k0 = 0; k0 < K; k0 += 64) {
#pragma unroll
    for (int i = 0; i < 4; i++) {
      int rr = (wv * 4 + i) * 8 + srow;
      int ldso = ((wv * 4 + i) * 64 + lane) * 8;
      gload16(&A[(size_t)(m0 + rr) * K + k0 + scol], &a_sm[ldso]);
      gload16(&B[(size_t)(n0 + rr) * K + k0 + scol], &b_sm[ldso]);
    }
    __syncthreads();
#pragma unroll
    for (int ks = 0; ks < 2; ks++) {
      bf16x8 af[4], bff[4];
#pragma unroll
      for (int t = 0; t < 4; t++) {
        af[t]  = *(const bf16x8*)&a_sm[(wrow + t * 16 + l16) * 64 + ks * 32 + quad * 8];
        bff[t] = *(const bf16x8*)&b_sm[(wcol + t * 16 + l16) * 64 + ks * 32 + quad * 8];
      }
#pragma unroll
      for (int mt = 0; mt < 4; mt++)
#pragma unroll
        for (int nt = 0; nt < 4; nt++)
          acc[mt][nt] = __builtin_amdgcn_mfma_f32_16x16x32_bf16(af[mt], bff[nt], acc[mt][nt], 0, 0, 0);
    }
    __syncthreads();
  }

#pragma unroll
  for (int nt = 0; nt < 4; nt++) {
    const int n = n0 + wcol + nt * 16 + l16;
    const float bv = bias[n];
#pragma unroll
    for (int mt = 0; mt < 4; mt++) {
      const int mb = m0 + wrow + mt * 16 + quad * 4;   // C/D row = quad*4 + reg
      if (mode == 0) {
#pragma unroll
        for (int r = 0; r < 4; r++) {
          int m = mb + r;
          int b = m >> 11, s = m & (S_LEN - 1);
          int h = n >> 6, d = n & 63;
          out[((size_t)(b * NH + h) * S_LEN + s) * DH + d] = f2bf((acc[mt][nt][r] + bv) * scale);
        }
      } else if (mode == 1) {
        int b = mb >> 11, s = mb & (S_LEN - 1);
        int h = n >> 6, d = n & 63;
        ushort4 o;
        o.x = f2bf((acc[mt][nt][0] + bv) * scale);
        o.y = f2bf((acc[mt][nt][1] + bv) * scale);
        o.z = f2bf((acc[mt][nt][2] + bv) * scale);
        o.w = f2bf((acc[mt][nt][3] + bv) * scale);
        *(ushort4*)&out[((size_t)(b * NH + h) * DH + d) * S_LEN + s] = o;
      } else {
#pragma unroll
        for (int r = 0; r < 4; r++) {
          int m = mb + r;
          outf[(size_t)m * EMB + n] = acc[mt][nt][r] + bv;
        }
      }
    }
  }
}

// Q, K, V projections in one launch: blockIdx.z selects the operand set.
// 8x32x3 = 768 blocks -> 3 blocks/CU (vs 1/CU for separate launches), so the
// per-K-step barrier drain of one block hides under the other two (m114 overlap).
__global__ __launch_bounds__(256) void gemm_qkv(
    const u16* __restrict__ xq, const u16* __restrict__ xk, const u16* __restrict__ xv,
    const u16* __restrict__ wq, const u16* __restrict__ wk, const u16* __restrict__ wv,
    const float* __restrict__ qb_f, const float* __restrict__ kb_f, const float* __restrict__ vb_f,
    u16* __restrict__ qo, u16* __restrict__ ko, u16* __restrict__ vt) {
  __shared__ u16 a_sm[128 * 64];
  __shared__ u16 b_sm[128 * 64];
  const int z = blockIdx.z;
  const u16* A = (z == 0) ? xq : (z == 1) ? xk : xv;
  const u16* B = (z == 0) ? wq : (z == 1) ? wk : wv;
  const float* bias = (z == 0) ? qb_f : (z == 1) ? kb_f : vb_f;
  u16* out = (z == 0) ? qo : (z == 1) ? ko : vt;
  float scale = (z == 0) ? 0.125f : 1.0f;   // Q pre-scaled by 1/sqrt(DH)
  int mode = (z == 2) ? 1 : 0;
  gemm_tile(a_sm, b_sm, A, B, bias, out, nullptr, EMB, scale, mode);
}

// Final O-projection (fp32 output).
__global__ __launch_bounds__(256) void gemm_o(
    const u16* __restrict__ A, const u16* __restrict__ B,
    const float* __restrict__ bias, float* __restrict__ outf) {
  __shared__ u16 a_sm[128 * 64];
  __shared__ u16 b_sm[128 * 64];
  gemm_tile(a_sm, b_sm, A, B, bias, nullptr, outf, EMB, 1.0f, 2);
}

// Fused attention: phase 1 computes softmax denominators (Q resident in regs),
// phase 2 recomputes scores (K hot in L2), writes normalized fp32 weights and
// accumulates O^T = Vt . P^T. The denominators never leave registers: after the
// 4-step shfl_xor butterfly over the l16 bits, EVERY lane holds the sums for its
// own (mt, r) rows, so no LDS/global broadcast is needed.
__global__ __launch_bounds__(256) void attn_fused(
    const u16* __restrict__ Qb, const u16* __restrict__ Kb,
    const u16* __restrict__ Vt, float* __restrict__ wout,
    u16* __restrict__ aout) {
  __shared__ u16 k_sm[128 * 64];
  __shared__ u16 vt_sm[64 * 128];
  __shared__ u16 p_sm[128 * 128];
  const int tid = threadIdx.x;
  const int lane = tid & 63, wv = tid >> 6;
  const int l16 = lane & 15, quad = lane >> 4;
  const int bh = blockIdx.y, q0 = blockIdx.x * 128;
  const u16* Qp = Qb + (size_t)bh * S_LEN * DH;
  const u16* Kp = Kb + (size_t)bh * S_LEN * DH;
  const u16* Vp = Vt + (size_t)bh * DH * S_LEN;
  const f32x4 fzero = {0.f, 0.f, 0.f, 0.f};

  // stage Q through k_sm once; pull per-wave fragments resident
#pragma unroll
  for (int i = 0; i < 4; i++) {
    int off = ((wv * 4 + i) * 64 + lane) * 8;   // tile is contiguous 16KB in global
    gload16(Qp + (size_t)q0 * DH + off, &k_sm[off]);
  }
  __syncthreads();
  bf16x8 aq[2][2];   // wave owns rows wv*32 .. wv*32+31, resident for both phases
#pragma unroll
  for (int mt = 0; mt < 2; mt++)
#pragma unroll
    for (int ks = 0; ks < 2; ks++)
      aq[mt][ks] = *(const bf16x8*)&k_sm[(wv * 32 + mt * 16 + l16) * 64 + ks * 32 + quad * 8];
  __syncthreads();   // k_sm gets overwritten below

  // ---- phase 1: row sums of exp(Qs.K) ----
  float racc[8];
#pragma unroll
  for (int i = 0; i < 8; i++) racc[i] = 0.f;

  for (int kt0 = 0; kt0 < S_LEN; kt0 += 128) {
#pragma unroll
    for (int i = 0; i < 4; i++) {
      int off = ((wv * 4 + i) * 64 + lane) * 8;
      gload16(Kp + (size_t)kt0 * DH + off, &k_sm[off]);
    }
    __syncthreads();
#pragma unroll
    for (int nt = 0; nt < 8; nt++) {
      bf16x8 bk0 = *(const bf16x8*)&k_sm[(nt * 16 + l16) * 64 + quad * 8];
      bf16x8 bk1 = *(const bf16x8*)&k_sm[(nt * 16 + l16) * 64 + 32 + quad * 8];
#pragma unroll
      for (int mt = 0; mt < 2; mt++) {
        f32x4 c = fzero;
        c = __builtin_amdgcn_mfma_f32_16x16x32_bf16(aq[mt][0], bk0, c, 0, 0, 0);
        c = __builtin_amdgcn_mfma_f32_16x16x32_bf16(aq[mt][1], bk1, c, 0, 0, 0);
#pragma unroll
        for (int r = 0; r < 4; r++) racc[mt * 4 + r] += __expf(c[r]);
      }
    }
    __syncthreads();
  }
#pragma unroll
  for (int i = 0; i < 8; i++) {
    racc[i] += __shfl_xor(racc[i], 1);
    racc[i] += __shfl_xor(racc[i], 2);
    racc[i] += __shfl_xor(racc[i], 4);
    racc[i] += __shfl_xor(racc[i], 8);
  }
  float il[2][4];
#pragma unroll
  for (int mt = 0; mt < 2; mt++)
#pragma unroll
    for (int r = 0; r < 4; r++) il[mt][r] = 1.0f / racc[mt * 4 + r];

  // ---- phase 2: normalized weights (fp32 to global, bf16 to p_sm) + O^T = Vt . P^T ----
  f32x4 oacc[8];     // O^T[d][q]: wave owns d rows wv*16..+15, all 128 q
#pragma unroll
  for (int i = 0; i < 8; i++) oacc[i] = fzero;

  const size_t rowbase = ((size_t)bh * S_LEN + q0) * S_LEN;

  for (int kt0 = 0; kt0 < S_LEN; kt0 += 128) {
#pragma unroll
    for (int i = 0; i < 4; i++) {
      int off = ((wv * 4 + i) * 64 + lane) * 8;
      gload16(Kp + (size_t)kt0 * DH + off, &k_sm[off]);
      gload16(Vp + (size_t)((wv * 4 + i) * 4 + quad) * S_LEN + kt0 + l16 * 8, &vt_sm[off]);
    }
    __syncthreads();

#pragma unroll
    for (int nt = 0; nt < 8; nt++) {
      bf16x8 bk0 = *(const bf16x8*)&k_sm[(nt * 16 + l16) * 64 + quad * 8];
      bf16x8 bk1 = *(const bf16x8*)&k_sm[(nt * 16 + l16) * 64 + 32 + quad * 8];
#pragma unroll
      for (int mt = 0; mt < 2; mt++) {
        f32x4 c = fzero;
        c = __builtin_amdgcn_mfma_f32_16x16x32_bf16(aq[mt][0], bk0, c, 0, 0, 0);
        c = __builtin_amdgcn_mfma_f32_16x16x32_bf16(aq[mt][1], bk1, c, 0, 0, 0);
#pragma unroll
        for (int r = 0; r < 4; r++) {
          float w = __expf(c[r]) * il[mt][r];
          int qlocal = wv * 32 + mt * 16 + quad * 4 + r;
          wout[rowbase + (size_t)qlocal * S_LEN + kt0 + nt * 16 + l16] = w;
          p_sm[qlocal * 128 + nt * 16 + l16] = f2bf(w);
        }
      }
    }
    __syncthreads();

    // O^T += Vt . P^T  (both frags contiguous-k)
    bf16x8 av[4];
#pragma unroll
    for (int ks = 0; ks < 4; ks++)
      av[ks] = *(const bf16x8*)&vt_sm[(wv * 16 + l16) * 128 + ks * 32 + quad * 8];
#pragma unroll
    for (int nt = 0; nt < 8; nt++)
#pragma unroll
      for (int ks = 0; ks < 4; ks++) {
        bf16x8 bp = *(const bf16x8*)&p_sm[(nt * 16 + l16) * 128 + ks * 32 + quad * 8];
        oacc[nt] = __builtin_amdgcn_mfma_f32_16x16x32_bf16(av[ks], bp, oacc[nt], 0, 0, 0);
      }
    __syncthreads();
  }

  // store attn_out [B,S,E] bf16: rows=d (quad*4+r) -> 4 consecutive d, 8B packed
  const int b = bh >> 4, h = bh & 15;
#pragma unroll
  for (int nt = 0; nt < 8; nt++) {
    int s = q0 + nt * 16 + l16;
    int d0 = wv * 16 + quad * 4;
    ushort4 o;
    o.x = f2bf(oacc[nt][0]);
    o.y = f2bf(oacc[nt][1]);
    o.z = f2bf(oacc[nt][2]);
    o.w = f2bf(oacc[nt][3]);
    *(ushort4*)&aout[(size_t)(b * S_LEN + s) * EMB + h * DH + d0] = o;
  }
}

extern "C" void kernel_launch(void* const* d_in, const int* in_sizes, int n_in,
                              void* d_out, int out_size, void* d_ws, size_t ws_size,
                              hipStream_t stream) {
  const float* q_f  = (const float*)d_in[0];
  const float* k_f  = (const float*)d_in[1];
  const float* v_f  = (const float*)d_in[2];
  const float* qw_f = (const float*)d_in[3];
  const float* qb_f = (const float*)d_in[4];
  const float* kw_f = (const float*)d_in[5];
  const float* kb_f = (const float*)d_in[6];
  const float* vw_f = (const float*)d_in[7];
  const float* vb_f = (const float*)d_in[8];
  const float* ow_f = (const float*)d_in[9];
  const float* ob_f = (const float*)d_in[10];

  uint8_t* wsb = (uint8_t*)d_ws;
  u16*   qb   = (u16*)(wsb + (size_t)(0u  << 20));  // [B,H,S,Dh] bf16, 8 MiB
  u16*   kb   = (u16*)(wsb + (size_t)(8u  << 20));  // [B,H,S,Dh]
  u16*   vt   = (u16*)(wsb + (size_t)(16u << 20));  // [B,H,Dh,S]
  u16*   xq   = (u16*)(wsb + (size_t)(24u << 20));  // activations bf16 [4096,1024]
  u16*   xk   = (u16*)(wsb + (size_t)(32u << 20));
  u16*   xv   = (u16*)(wsb + (size_t)(40u << 20));
  u16*   wq   = (u16*)(wsb + (size_t)(48u << 20));  // weights bf16 [1024,1024], 2 MiB
  u16*   wk   = (u16*)(wsb + (size_t)(50u << 20));
  u16*   wvw  = (u16*)(wsb + (size_t)(52u << 20));
  u16*   wo   = (u16*)(wsb + (size_t)(54u << 20));
  u16*   ao   = (u16*)(wsb + (size_t)(57u << 20));  // attn_out bf16 [4096,1024], 8 MiB
  // total 65 MiB of workspace

  // 1) all fp32->bf16 conversions in one launch (4M float4s)
  cvt_all<<<(1 << 22) / 256, 256, 0, stream>>>(
      q_f, k_f, v_f, qw_f, kw_f, vw_f, ow_f,
      xq, xk, xv, wq, wk, wvw, wo);

  // 2) Q,K,V projections in one launch (768 blocks -> 3 blocks/CU)
  dim3 gqkv(8, 32, 3);   // N/128, M/128, {Q,K,V}
  gemm_qkv<<<gqkv, 256, 0, stream>>>(xq, xk, xv, wq, wk, wvw, qb_f, kb_f, vb_f, qb, kb, vt);

  // 3) fused two-phase attention (denominators stay in registers)
  float* outp = (float*)d_out;
  dim3 ga(16, 32);  // S/128 q-tiles, B*H
  attn_fused<<<ga, 256, 0, stream>>>(qb, kb, vt, outp + (size_t)2 * S_LEN * EMB, ao);

  // 4) output projection
  dim3 gp(8, 32);
  gemm_o<<<gp, 256, 0, stream>>>(ao, wo, ob_f, outp);
}

// Round 2
// 771.833 us; speedup vs baseline: 1.1093x; 1.0400x over previous
//
#include <hip/hip_runtime.h>
#include <cstdint>
#include <cstddef>

#define S_LEN 2048
#define EMB   1024
#define NH    16
#define DH    64

typedef unsigned short u16;
typedef __attribute__((ext_vector_type(8))) short bf16x8;   // 8 bf16 (4 VGPRs)
typedef __attribute__((ext_vector_type(4))) float f32x4;

__device__ __forceinline__ u16 f2bf(float f) {
  unsigned int u = __float_as_uint(f);
  u = (u + 0x7fffu + ((u >> 16) & 1u)) >> 16;   // RNE
  return (u16)u;
}

__device__ __forceinline__ void gload16(const void* g, void* l) {
  __builtin_amdgcn_global_load_lds(
      (const __attribute__((address_space(1))) unsigned int*)g,
      (__attribute__((address_space(3))) unsigned int*)l, 16, 0, 0);
}

// One launch converts all 7 fp32 inputs to bf16.
__global__ void cvt_all(
    const float* __restrict__ q_f, const float* __restrict__ k_f, const float* __restrict__ v_f,
    const float* __restrict__ qw_f, const float* __restrict__ kw_f,
    const float* __restrict__ vw_f, const float* __restrict__ ow_f,
    u16* __restrict__ xq, u16* __restrict__ xk, u16* __restrict__ xv,
    u16* __restrict__ wq, u16* __restrict__ wk, u16* __restrict__ wv, u16* __restrict__ wo) {
  int i = blockIdx.x * blockDim.x + threadIdx.x;
  const float* src;
  u16* dst;
  int off;
  if (i < (3 << 20)) {
    int r = i >> 20;
    off = i & ((1 << 20) - 1);
    src = (r == 0) ? q_f : (r == 1) ? k_f : v_f;
    dst = (r == 0) ? xq  : (r == 1) ? xk  : xv;
  } else {
    int j = i - (3 << 20);
    int r = j >> 18;
    off = j & ((1 << 18) - 1);
    src = (r == 0) ? qw_f : (r == 1) ? kw_f : (r == 2) ? vw_f : ow_f;
    dst = (r == 0) ? wq   : (r == 1) ? wk   : (r == 2) ? wv   : wo;
  }
  float4 v = ((const float4*)src)[off];
  ushort4 o;
  o.x = f2bf(v.x); o.y = f2bf(v.y); o.z = f2bf(v.z); o.w = f2bf(v.w);
  ((ushort4*)dst)[off] = o;
}

// C[m,n] = (sum_k A[m,k]*B[n,k] + bias[n]) * scale
// mode 0: out[((b*NH+h)*S + s)*DH + d]   (Q,K -> [B,H,S,Dh] bf16)
// mode 1: out[((b*NH+h)*DH + d)*S + s]   (V   -> [B,H,Dh,S] bf16, transposed)
// mode 2: outf[m*EMB + n]                (final output, fp32 row-major)
__device__ __forceinline__ void gemm_tile(
    u16* a_sm, u16* b_sm,
    const u16* __restrict__ A, const u16* __restrict__ B,
    const float* __restrict__ bias, u16* __restrict__ out,
    float* __restrict__ outf, int K, float scale, int mode) {
  const int tid = threadIdx.x;
  const int lane = tid & 63, wv = tid >> 6;
  const int l16 = lane & 15, quad = lane >> 4;
  const int m0 = blockIdx.y * 128, n0 = blockIdx.x * 128;
  const int wrow = (wv >> 1) * 64, wcol = (wv & 1) * 64;
  const f32x4 fzero = {0.f, 0.f, 0.f, 0.f};

  f32x4 acc[4][4];
#pragma unroll
  for (int i = 0; i < 4; i++)
#pragma unroll
    for (int j = 0; j < 4; j++) acc[i][j] = fzero;

  const int srow = lane >> 3;        // 0..7 (row within 8-row chunk)
  const int scol = (lane & 7) * 8;   // element offset (8 bf16 = 16B)

  for (int k0 = 0; k0 < K; k0 += 64) {
#pragma unroll
    for (int i = 0; i < 4; i++) {
      int rr = (wv * 4 + i) * 8 + srow;
      int ldso = ((wv * 4 + i) * 64 + lane) * 8;
      gload16(&A[(size_t)(m0 + rr) * K + k0 + scol], &a_sm[ldso]);
      gload16(&B[(size_t)(n0 + rr) * K + k0 + scol], &b_sm[ldso]);
    }
    __syncthreads();
#pragma unroll
    for (int ks = 0; ks < 2; ks++) {
      bf16x8 af[4], bff[4];
#pragma unroll
      for (int t = 0; t < 4; t++) {
        af[t]  = *(const bf16x8*)&a_sm[(wrow + t * 16 + l16) * 64 + ks * 32 + quad * 8];
        bff[t] = *(const bf16x8*)&b_sm[(wcol + t * 16 + l16) * 64 + ks * 32 + quad * 8];
      }
#pragma unroll
      for (int mt = 0; mt < 4; mt++)
#pragma unroll
        for (int nt = 0; nt < 4; nt++)
          acc[mt][nt] = __builtin_amdgcn_mfma_f32_16x16x32_bf16(af[mt], bff[nt], acc[mt][nt], 0, 0, 0);
    }
    __syncthreads();
  }

#pragma unroll
  for (int nt = 0; nt < 4; nt++) {
    const int n = n0 + wcol + nt * 16 + l16;
    const float bv = bias[n];
#pragma unroll
    for (int mt = 0; mt < 4; mt++) {
      const int mb = m0 + wrow + mt * 16 + quad * 4;   // C/D row = quad*4 + reg
      if (mode == 0) {
#pragma unroll
        for (int r = 0; r < 4; r++) {
          int m = mb + r;
          int b = m >> 11, s = m & (S_LEN - 1);
          int h = n >> 6, d = n & 63;
          out[((size_t)(b * NH + h) * S_LEN + s) * DH + d] = f2bf((acc[mt][nt][r] + bv) * scale);
        }
      } else if (mode == 1) {
        int b = mb >> 11, s = mb & (S_LEN - 1);
        int h = n >> 6, d = n & 63;
        ushort4 o;
        o.x = f2bf((acc[mt][nt][0] + bv) * scale);
        o.y = f2bf((acc[mt][nt][1] + bv) * scale);
        o.z = f2bf((acc[mt][nt][2] + bv) * scale);
        o.w = f2bf((acc[mt][nt][3] + bv) * scale);
        *(ushort4*)&out[((size_t)(b * NH + h) * DH + d) * S_LEN + s] = o;
      } else {
#pragma unroll
        for (int r = 0; r < 4; r++) {
          int m = mb + r;
          outf[(size_t)m * EMB + n] = acc[mt][nt][r] + bv;
        }
      }
    }
  }
}

// Q, K, V projections in one launch: blockIdx.z selects the operand set.
__global__ __launch_bounds__(256) void gemm_qkv(
    const u16* __restrict__ xq, const u16* __restrict__ xk, const u16* __restrict__ xv,
    const u16* __restrict__ wq, const u16* __restrict__ wk, const u16* __restrict__ wv,
    const float* __restrict__ qb_f, const float* __restrict__ kb_f, const float* __restrict__ vb_f,
    u16* __restrict__ qo, u16* __restrict__ ko, u16* __restrict__ vt) {
  __shared__ u16 a_sm[128 * 64];
  __shared__ u16 b_sm[128 * 64];
  const int z = blockIdx.z;
  const u16* A = (z == 0) ? xq : (z == 1) ? xk : xv;
  const u16* B = (z == 0) ? wq : (z == 1) ? wk : wv;
  const float* bias = (z == 0) ? qb_f : (z == 1) ? kb_f : vb_f;
  u16* out = (z == 0) ? qo : (z == 1) ? ko : vt;
  float scale = (z == 0) ? 0.125f : 1.0f;   // Q pre-scaled by 1/sqrt(DH)
  int mode = (z == 2) ? 1 : 0;
  gemm_tile(a_sm, b_sm, A, B, bias, out, nullptr, EMB, scale, mode);
}

// Final O-projection (fp32 output).
__global__ __launch_bounds__(256) void gemm_o(
    const u16* __restrict__ A, const u16* __restrict__ B,
    const float* __restrict__ bias, float* __restrict__ outf) {
  __shared__ u16 a_sm[128 * 64];
  __shared__ u16 b_sm[128 * 64];
  gemm_tile(a_sm, b_sm, A, B, bias, nullptr, outf, EMB, 1.0f, 2);
}

// Fused attention, XOR-swizzled LDS (T2 / m214 "+89%" fix):
//   k_sm  [128][64]  u16 (128 B rows): element (r,c) at u16 addr r*64 + (c ^ ((r&7)<<3))
//   vt_sm [64][128]  u16 (256 B rows): element (r,c) at u16 addr r*128 + (c ^ ((r&7)<<3))
//   p_sm  [128][128] u16 (256 B rows): element (r,c) at u16 addr r*128 + (c ^ ((r&15)<<3))
// k_sm/vt_sm are filled by global_load_lds with a LINEAR LDS dest and the
// inverse permutation applied to the per-lane GLOBAL source column (rule 21 /
// m173: same involution on both sides). Keys are multiples of 8 u16 (one 16 B
// chunk), so b128 reads stay element-contiguous. All frag-read rows satisfy
// row&7 == l16&7 (row&15 == l16 for p_sm), so the read-side XOR is lane-derived.
__global__ __launch_bounds__(256) void attn_fused(
    const u16* __restrict__ Qb, const u16* __restrict__ Kb,
    const u16* __restrict__ Vt, float* __restrict__ wout,
    u16* __restrict__ aout) {
  __shared__ u16 k_sm[128 * 64];
  __shared__ u16 vt_sm[64 * 128];
  __shared__ u16 p_sm[128 * 128];
  const int tid = threadIdx.x;
  const int lane = tid & 63, wv = tid >> 6;
  const int l16 = lane & 15, quad = lane >> 4;
  const int bh = blockIdx.y, q0 = blockIdx.x * 128;
  const u16* Qp = Qb + (size_t)bh * S_LEN * DH;
  const u16* Kp = Kb + (size_t)bh * S_LEN * DH;
  const u16* Vp = Vt + (size_t)bh * DH * S_LEN;
  const f32x4 fzero = {0.f, 0.f, 0.f, 0.f};

  const int srow8 = lane >> 3;                               // 0..7
  const int kswz  = (((lane & 7) ^ (srow8 & 7)) << 3);       // pre-swizzled src col (u16) for k_sm rows
  const int kc    = (l16 & 7) << 3;                          // read-side XOR key for k_sm / vt_sm
  const int pc    = l16 << 3;                                // read-side XOR key for p_sm (row&15 == l16)

  // stage Q through k_sm once (swizzled); pull per-wave fragments resident
#pragma unroll
  for (int i = 0; i < 4; i++) {
    int r = (wv * 4 + i) * 8 + srow8;                        // row within 128-row tile
    gload16(Qp + (size_t)(q0 + r) * DH + kswz, &k_sm[((wv * 4 + i) * 64 + lane) * 8]);
  }
  __syncthreads();
  bf16x8 aq[2][2];   // wave owns rows wv*32 .. wv*32+31, resident for both phases
#pragma unroll
  for (int mt = 0; mt < 2; mt++)
#pragma unroll
    for (int ks = 0; ks < 2; ks++)
      aq[mt][ks] = *(const bf16x8*)&k_sm[(wv * 32 + mt * 16 + l16) * 64 + ((ks * 32 + quad * 8) ^ kc)];
  __syncthreads();   // k_sm gets overwritten below

  // ---- phase 1: row sums of exp(Qs.K) ----
  float racc[8];
#pragma unroll
  for (int i = 0; i < 8; i++) racc[i] = 0.f;

  for (int kt0 = 0; kt0 < S_LEN; kt0 += 128) {
#pragma unroll
    for (int i = 0; i < 4; i++) {
      int r = (wv * 4 + i) * 8 + srow8;
      gload16(Kp + (size_t)(kt0 + r) * DH + kswz, &k_sm[((wv * 4 + i) * 64 + lane) * 8]);
    }
    __syncthreads();
#pragma unroll
    for (int nt = 0; nt < 8; nt++) {
      int krow = (nt * 16 + l16) * 64;
      bf16x8 bk0 = *(const bf16x8*)&k_sm[krow + ((quad * 8) ^ kc)];
      bf16x8 bk1 = *(const bf16x8*)&k_sm[krow + ((32 + quad * 8) ^ kc)];
#pragma unroll
      for (int mt = 0; mt < 2; mt++) {
        f32x4 c = fzero;
        c = __builtin_amdgcn_mfma_f32_16x16x32_bf16(aq[mt][0], bk0, c, 0, 0, 0);
        c = __builtin_amdgcn_mfma_f32_16x16x32_bf16(aq[mt][1], bk1, c, 0, 0, 0);
#pragma unroll
        for (int r = 0; r < 4; r++) racc[mt * 4 + r] += __expf(c[r]);
      }
    }
    __syncthreads();
  }
#pragma unroll
  for (int i = 0; i < 8; i++) {
    racc[i] += __shfl_xor(racc[i], 1);
    racc[i] += __shfl_xor(racc[i], 2);
    racc[i] += __shfl_xor(racc[i], 4);
    racc[i] += __shfl_xor(racc[i], 8);
  }
  float il[2][4];
#pragma unroll
  for (int mt = 0; mt < 2; mt++)
#pragma unroll
    for (int r = 0; r < 4; r++) il[mt][r] = 1.0f / racc[mt * 4 + r];

  // ---- phase 2: normalized weights (fp32 to global, bf16 to p_sm) + O^T = Vt . P^T ----
  f32x4 oacc[8];     // O^T[d][q]: wave owns d rows wv*16..+15, all 128 q
#pragma unroll
  for (int i = 0; i < 8; i++) oacc[i] = fzero;

  const size_t rowbase = ((size_t)bh * S_LEN + q0) * S_LEN;

  for (int kt0 = 0; kt0 < S_LEN; kt0 += 128) {
#pragma unroll
    for (int i = 0; i < 4; i++) {
      int r = (wv * 4 + i) * 8 + srow8;
      int dst = ((wv * 4 + i) * 64 + lane) * 8;
      gload16(Kp + (size_t)(kt0 + r) * DH + kswz, &k_sm[dst]);
      int drow = (wv * 4 + i) * 4 + quad;
      int vswz = (l16 * 8) ^ ((drow & 7) << 3);
      gload16(Vp + (size_t)drow * S_LEN + kt0 + vswz, &vt_sm[dst]);
    }
    __syncthreads();

#pragma unroll
    for (int nt = 0; nt < 8; nt++) {
      int krow = (nt * 16 + l16) * 64;
      bf16x8 bk0 = *(const bf16x8*)&k_sm[krow + ((quad * 8) ^ kc)];
      bf16x8 bk1 = *(const bf16x8*)&k_sm[krow + ((32 + quad * 8) ^ kc)];
#pragma unroll
      for (int mt = 0; mt < 2; mt++) {
        f32x4 c = fzero;
        c = __builtin_amdgcn_mfma_f32_16x16x32_bf16(aq[mt][0], bk0, c, 0, 0, 0);
        c = __builtin_amdgcn_mfma_f32_16x16x32_bf16(aq[mt][1], bk1, c, 0, 0, 0);
#pragma unroll
        for (int r = 0; r < 4; r++) {
          float w = __expf(c[r]) * il[mt][r];
          int qlocal = wv * 32 + mt * 16 + quad * 4 + r;
          wout[rowbase + (size_t)qlocal * S_LEN + kt0 + nt * 16 + l16] = w;
          p_sm[qlocal * 128 + ((nt * 16 + l16) ^ ((qlocal & 15) << 3))] = f2bf(w);
        }
      }
    }
    __syncthreads();

    // O^T += Vt . P^T  (both frags contiguous-k, swizzle-corrected reads)
    bf16x8 av[4];
#pragma unroll
    for (int ks = 0; ks < 4; ks++)
      av[ks] = *(const bf16x8*)&vt_sm[(wv * 16 + l16) * 128 + ((ks * 32 + quad * 8) ^ kc)];
#pragma unroll
    for (int nt = 0; nt < 8; nt++)
#pragma unroll
      for (int ks = 0; ks < 4; ks++) {
        bf16x8 bp = *(const bf16x8*)&p_sm[(nt * 16 + l16) * 128 + ((ks * 32 + quad * 8) ^ pc)];
        oacc[nt] = __builtin_amdgcn_mfma_f32_16x16x32_bf16(av[ks], bp, oacc[nt], 0, 0, 0);
      }
    __syncthreads();
  }

  // store attn_out [B,S,E] bf16: rows=d (quad*4+r) -> 4 consecutive d, 8B packed
  const int b = bh >> 4, h = bh & 15;
#pragma unroll
  for (int nt = 0; nt < 8; nt++) {
    int s = q0 + nt * 16 + l16;
    int d0 = wv * 16 + quad * 4;
    ushort4 o;
    o.x = f2bf(oacc[nt][0]);
    o.y = f2bf(oacc[nt][1]);
    o.z = f2bf(oacc[nt][2]);
    o.w = f2bf(oacc[nt][3]);
    *(ushort4*)&aout[(size_t)(b * S_LEN + s) * EMB + h * DH + d0] = o;
  }
}

extern "C" void kernel_launch(void* const* d_in, const int* in_sizes, int n_in,
                              void* d_out, int out_size, void* d_ws, size_t ws_size,
                              hipStream_t stream) {
  const float* q_f  = (const float*)d_in[0];
  const float* k_f  = (const float*)d_in[1];
  const float* v_f  = (const float*)d_in[2];
  const float* qw_f = (const float*)d_in[3];
  const float* qb_f = (const float*)d_in[4];
  const float* kw_f = (const float*)d_in[5];
  const float* kb_f = (const float*)d_in[6];
  const float* vw_f = (const float*)d_in[7];
  const float* vb_f = (const float*)d_in[8];
  const float* ow_f = (const float*)d_in[9];
  const float* ob_f = (const float*)d_in[10];

  uint8_t* wsb = (uint8_t*)d_ws;
  u16*   qb   = (u16*)(wsb + (size_t)(0u  << 20));  // [B,H,S,Dh] bf16, 8 MiB
  u16*   kb   = (u16*)(wsb + (size_t)(8u  << 20));  // [B,H,S,Dh]
  u16*   vt   = (u16*)(wsb + (size_t)(16u << 20));  // [B,H,Dh,S]
  u16*   xq   = (u16*)(wsb + (size_t)(24u << 20));  // activations bf16 [4096,1024]
  u16*   xk   = (u16*)(wsb + (size_t)(32u << 20));
  u16*   xv   = (u16*)(wsb + (size_t)(40u << 20));
  u16*   wq   = (u16*)(wsb + (size_t)(48u << 20));  // weights bf16 [1024,1024], 2 MiB
  u16*   wk   = (u16*)(wsb + (size_t)(50u << 20));
  u16*   wvw  = (u16*)(wsb + (size_t)(52u << 20));
  u16*   wo   = (u16*)(wsb + (size_t)(54u << 20));
  u16*   ao   = (u16*)(wsb + (size_t)(57u << 20));  // attn_out bf16 [4096,1024], 8 MiB
  // total 65 MiB of workspace

  // 1) all fp32->bf16 conversions in one launch (4M float4s)
  cvt_all<<<(1 << 22) / 256, 256, 0, stream>>>(
      q_f, k_f, v_f, qw_f, kw_f, vw_f, ow_f,
      xq, xk, xv, wq, wk, wvw, wo);

  // 2) Q,K,V projections in one launch (768 blocks -> 3 blocks/CU)
  dim3 gqkv(8, 32, 3);   // N/128, M/128, {Q,K,V}
  gemm_qkv<<<gqkv, 256, 0, stream>>>(xq, xk, xv, wq, wk, wvw, qb_f, kb_f, vb_f, qb, kb, vt);

  // 3) fused two-phase attention (denominators stay in registers)
  float* outp = (float*)d_out;
  dim3 ga(16, 32);  // S/128 q-tiles, B*H
  attn_fused<<<ga, 256, 0, stream>>>(qb, kb, vt, outp + (size_t)2 * S_LEN * EMB, ao);

  // 4) output projection
  dim3 gp(8, 32);
  gemm_o<<<gp, 256, 0, stream>>>(ao, wo, ob_f, outp);
}